// Round 12
// baseline (393.673 us; speedup 1.0000x reference)
//
#include <hip/hip_runtime.h>

#define NODES  30000
#define EDGES  480000
#define GRAPHS 500
#define MPAD   30016   // 64*469
#define NB     118     // scan blocks: ceil(30000/256)

typedef __bf16 bf16x8 __attribute__((ext_vector_type(8)));
typedef float  f32x4  __attribute__((ext_vector_type(4)));

__device__ __forceinline__ float4 f4add(float4 a, float4 b) {
    a.x += b.x; a.y += b.y; a.z += b.z; a.w += b.w; return a;
}

// ---------------- fp32 -> bf16 hi/lo split (RNE both halves) ----------------
__device__ __forceinline__ void split_f32(float a, unsigned short& hi, unsigned short& lo) {
    unsigned int u = __float_as_uint(a);
    unsigned int rh = (u + 0x7fffu + ((u >> 16) & 1u)) & 0xffff0000u;
    hi = (unsigned short)(rh >> 16);
    float l = a - __uint_as_float(rh);
    unsigned int ul = __float_as_uint(l);
    lo = (unsigned short)((ul + 0x7fffu + ((ul >> 16) & 1u)) >> 16);
}

__device__ __forceinline__ void gload_lds16(const void* g, void* l) {
    __builtin_amdgcn_global_load_lds(
        (__attribute__((address_space(1))) void*)g,
        (__attribute__((address_space(3))) void*)l, 16, 0, 0);
}

// ---------------- CSR build ----------------
__global__ void count_kernel(const int* __restrict__ dst, int* __restrict__ cnt, int E) {
    int i = blockIdx.x * blockDim.x + threadIdx.x;
    if (i < E) atomicAdd(&cnt[dst[i]], 1);
}

__global__ __launch_bounds__(256) void scan_bsum_kernel(const int* __restrict__ cnt,
                                                        int* __restrict__ bsum, int n) {
    __shared__ int buf[256];
    int t = threadIdx.x;
    int i = blockIdx.x * 256 + t;
    buf[t] = (i < n) ? cnt[i] : 0;
    __syncthreads();
    for (int ofs = 128; ofs > 0; ofs >>= 1) {
        if (t < ofs) buf[t] += buf[t + ofs];
        __syncthreads();
    }
    if (t == 0) bsum[blockIdx.x] = buf[0];
}

__global__ __launch_bounds__(128) void scan_top_kernel(const int* __restrict__ bsum,
                                                       int* __restrict__ boff) {
    __shared__ int buf[128];
    int t = threadIdx.x;
    int own = (t < NB) ? bsum[t] : 0;
    buf[t] = own;
    __syncthreads();
    for (int ofs = 1; ofs < 128; ofs <<= 1) {
        int v = (t >= ofs) ? buf[t - ofs] : 0;
        __syncthreads();
        buf[t] += v;
        __syncthreads();
    }
    if (t < NB) boff[t] = buf[t] - own;
}

__global__ __launch_bounds__(256) void scan_apply_kernel(const int* __restrict__ cnt,
                                                         const int* __restrict__ boff,
                                                         int* __restrict__ rowstart,
                                                         float* __restrict__ dinv, int n) {
    __shared__ int buf[256];
    int t = threadIdx.x;
    int i = blockIdx.x * 256 + t;
    int own = (i < n) ? cnt[i] : 0;
    buf[t] = own;
    __syncthreads();
    for (int ofs = 1; ofs < 256; ofs <<= 1) {
        int v = (t >= ofs) ? buf[t - ofs] : 0;
        __syncthreads();
        buf[t] += v;
        __syncthreads();
    }
    if (i < n) {
        rowstart[i] = boff[blockIdx.x] + buf[t] - own;
        dinv[i] = rsqrtf((float)own + 1.0f);
    }
}

__global__ void fill_kernel(const int* __restrict__ src, const int* __restrict__ dst,
                            const int* __restrict__ rowstart, int* __restrict__ cursor,
                            int* __restrict__ csr_src, int E) {
    int i = blockIdx.x * blockDim.x + threadIdx.x;
    if (i < E) {
        int d = dst[i];
        int pos = atomicAdd(&cursor[d], 1);
        csr_src[rowstart[d] + pos] = src[i];
    }
}

// ---------------- pre-scale into padded stride-80 layout ----------------
__global__ void prescale_kernel(const float* __restrict__ X, const float* __restrict__ dinv,
                                float* __restrict__ Xs, int total) {
    int i = blockIdx.x * blockDim.x + threadIdx.x;
    if (i < total) {
        int node = i / 80;
        int c = i - node * 80;
        Xs[i] = (c < 78) ? X[node * 78 + c] * dinv[node] : 0.0f;
    }
}

// ---------------- weight split+transpose ----------------
__global__ void wsplit_kernel(const float* __restrict__ W, unsigned short* __restrict__ hi,
                              unsigned short* __restrict__ lo, int K, int N, int Kp) {
    int n = blockIdx.x, k = threadIdx.x;
    float v = (n < N && k < K) ? W[(size_t)k * N + n] : 0.0f;
    unsigned short h, l;
    split_f32(v, h, l);
    hi[(size_t)n * Kp + k] = h;
    lo[(size_t)n * Kp + k] = l;
}

// ---------------- half-row aggregation pass (layers 1/2): L2-resident 4.8 MB slice ----------------
// Table rows stride RS4 float4; this pass reads float4s [SOFF, SOFF+DV) of each row.
// DV=10, EPI=6: 6 edges per gather instruction, 60/64 lanes active.
// Output bf16 slots CB4+lane (lane<DV); ZPAD zero slots after.
template <int DV, int RS4, int SOFF, int CB4, int ZPAD, int KQ>
__global__ __launch_bounds__(256) void agg_half(
    const float* __restrict__ Xs, const int* __restrict__ rowstart,
    const int* __restrict__ cnt, const int* __restrict__ csr_src,
    const float* __restrict__ dinv,
    unsigned short* __restrict__ ohi, unsigned short* __restrict__ olo)
{
    constexpr int EPI = 64 / DV;     // 6
    constexpr int Kp = KQ * 4;
    int node = blockIdx.x * 4 + (threadIdx.x >> 6);
    int lane = threadIdx.x & 63;
    int sub = lane / DV;
    int c4 = lane - sub * DV;
    const float4* X4 = (const float4*)Xs;

    float4 acc0 = {0.f, 0.f, 0.f, 0.f}, acc1 = {0.f, 0.f, 0.f, 0.f};
    int s = rowstart[node];
    int e = s + cnt[node];

    if (sub < EPI) {
        if (sub == 0) acc0 = X4[(size_t)node * RS4 + SOFF + c4];   // self term
        int j = s;
        for (; j + 2 * EPI <= e; j += 2 * EPI) {
            int i0 = csr_src[j + sub];
            int i1 = csr_src[j + EPI + sub];
            float4 x0 = X4[(size_t)i0 * RS4 + SOFF + c4];
            float4 x1 = X4[(size_t)i1 * RS4 + SOFF + c4];
            acc0 = f4add(acc0, x0);
            acc1 = f4add(acc1, x1);
        }
        for (; j < e; j += EPI) {
            int jj = j + sub;
            if (jj < e) {
                int idx = csr_src[jj];
                acc0 = f4add(acc0, X4[(size_t)idx * RS4 + SOFF + c4]);
            }
        }
    }
    float4 acc = f4add(acc0, acc1);

    // read ALL shuffle sources before accumulating (lanes<DV: sources <64, no wrap/RAW)
    {
        float sx[EPI - 1], sy[EPI - 1], sz[EPI - 1], sw[EPI - 1];
        #pragma unroll
        for (int sft = 1; sft < EPI; sft++) {
            sx[sft - 1] = __shfl(acc.x, lane + sft * DV);
            sy[sft - 1] = __shfl(acc.y, lane + sft * DV);
            sz[sft - 1] = __shfl(acc.z, lane + sft * DV);
            sw[sft - 1] = __shfl(acc.w, lane + sft * DV);
        }
        #pragma unroll
        for (int sft = 1; sft < EPI; sft++) {
            acc.x += sx[sft - 1];
            acc.y += sy[sft - 1];
            acc.z += sz[sft - 1];
            acc.w += sw[sft - 1];
        }
    }

    if (lane < DV) {
        float di = dinv[node];
        ushort4 h4, l4;
        split_f32(acc.x * di, h4.x, l4.x);
        split_f32(acc.y * di, h4.y, l4.y);
        split_f32(acc.z * di, h4.z, l4.z);
        split_f32(acc.w * di, h4.w, l4.w);
        *(ushort4*)&ohi[(size_t)node * Kp + (CB4 + lane) * 4] = h4;
        *(ushort4*)&olo[(size_t)node * Kp + (CB4 + lane) * 4] = l4;
    } else if (lane < DV + ZPAD) {
        ushort4 z = {0, 0, 0, 0};
        *(ushort4*)&ohi[(size_t)node * Kp + (CB4 + lane) * 4] = z;
        *(ushort4*)&olo[(size_t)node * Kp + (CB4 + lane) * 4] = z;
    }
}

// ---------------- layer-3 aggregation (full 640B rows, compulsory-bound) ----------------
template <int DV, int KQ>
__global__ __launch_bounds__(256) void agg_split_v3(
    const float* __restrict__ Xs, const int* __restrict__ rowstart,
    const int* __restrict__ cnt, const int* __restrict__ csr_src,
    const float* __restrict__ dinv,
    unsigned short* __restrict__ ohi, unsigned short* __restrict__ olo)
{
    constexpr int EPI = 64 / DV;
    constexpr int Kp = KQ * 4;
    int node = blockIdx.x * 4 + (threadIdx.x >> 6);
    int lane = threadIdx.x & 63;
    int sub = lane / DV;
    int c4 = lane - sub * DV;
    const float4* X4 = (const float4*)Xs;

    float4 acc0 = {0.f, 0.f, 0.f, 0.f}, acc1 = {0.f, 0.f, 0.f, 0.f};
    float4 acc2 = {0.f, 0.f, 0.f, 0.f}, acc3 = {0.f, 0.f, 0.f, 0.f};
    int s = rowstart[node];
    int e = s + cnt[node];

    if (sub < EPI) {
        if (sub == 0) acc0 = X4[(size_t)node * DV + c4];
        int j = s;
        for (; j + 4 * EPI <= e; j += 4 * EPI) {
            int i0 = csr_src[j + sub],           i1 = csr_src[j + EPI + sub];
            int i2 = csr_src[j + 2 * EPI + sub], i3 = csr_src[j + 3 * EPI + sub];
            float4 x0 = X4[(size_t)i0 * DV + c4], x1 = X4[(size_t)i1 * DV + c4];
            float4 x2 = X4[(size_t)i2 * DV + c4], x3 = X4[(size_t)i3 * DV + c4];
            acc0 = f4add(acc0, x0); acc1 = f4add(acc1, x1);
            acc2 = f4add(acc2, x2); acc3 = f4add(acc3, x3);
        }
        for (; j < e; j += EPI) {
            int jj = j + sub;
            if (jj < e) {
                int idx = csr_src[jj];
                acc0 = f4add(acc0, X4[(size_t)idx * DV + c4]);
            }
        }
    }
    float4 acc = f4add(f4add(acc0, acc1), f4add(acc2, acc3));

    if constexpr (EPI > 1) {
        float sx[EPI - 1], sy[EPI - 1], sz[EPI - 1], sw[EPI - 1];
        #pragma unroll
        for (int sft = 1; sft < EPI; sft++) {
            sx[sft - 1] = __shfl(acc.x, lane + sft * DV);
            sy[sft - 1] = __shfl(acc.y, lane + sft * DV);
            sz[sft - 1] = __shfl(acc.z, lane + sft * DV);
            sw[sft - 1] = __shfl(acc.w, lane + sft * DV);
        }
        #pragma unroll
        for (int sft = 1; sft < EPI; sft++) {
            acc.x += sx[sft - 1];
            acc.y += sy[sft - 1];
            acc.z += sz[sft - 1];
            acc.w += sw[sft - 1];
        }
    }

    if (lane < DV) {
        float di = dinv[node];
        ushort4 h4, l4;
        split_f32(acc.x * di, h4.x, l4.x);
        split_f32(acc.y * di, h4.y, l4.y);
        split_f32(acc.z * di, h4.z, l4.z);
        split_f32(acc.w * di, h4.w, l4.w);
        *(ushort4*)&ohi[(size_t)node * Kp + lane * 4] = h4;
        *(ushort4*)&olo[(size_t)node * Kp + lane * 4] = l4;
    } else if (lane < KQ) {
        ushort4 z = {0, 0, 0, 0};
        *(ushort4*)&ohi[(size_t)node * Kp + lane * 4] = z;
        *(ushort4*)&olo[(size_t)node * Kp + lane * 4] = z;
    }
}

// ---------------- split-bf16 MFMA GEMM: row-persistent, in-kernel column loop ----------------
template <int NCK>
__global__ __launch_bounds__(256) void mfma_gemm_v2(
    const unsigned short* __restrict__ Ahi, const unsigned short* __restrict__ Alo,
    const unsigned short* __restrict__ Bhi, const unsigned short* __restrict__ Blo,
    const float* __restrict__ bias, const float* __restrict__ scale,
    float* __restrict__ C, int M, int N, int Cstride, int nN, int do_relu)
{
    constexpr int Kp = NCK * 32;
    constexpr int CELLS = NCK * 256;
    extern __shared__ unsigned short smem[];
    unsigned short* sA = smem;
    unsigned short* sB = smem + 2 * CELLS * 8;

    int t = threadIdx.x;
    int wv = t >> 6, ln = t & 63;
    int q = ln >> 4, l16 = ln & 15;
    int wm = wv & 1, wn = wv >> 1;
    int m0 = blockIdx.x * 64;

    #pragma unroll
    for (int i = 0; i < 2 * NCK; i++) {
        int c = i * 256 + t;
        int plane = c / CELLS;
        int r = c - plane * CELLS;
        int ck = r >> 8, qq = (r >> 6) & 3, row = r & 63;
        const unsigned short* src = (plane ? Alo : Ahi) + (size_t)(m0 + row) * Kp + ck * 32 + qq * 8;
        gload_lds16(src, &sA[(size_t)c * 8]);
    }

    for (int nt = 0; nt < nN; nt++) {
        int n0 = nt * 64;
        if (nt > 0) __syncthreads();
        #pragma unroll
        for (int i = 0; i < 2 * NCK; i++) {
            int c = i * 256 + t;
            int plane = c / CELLS;
            int r = c - plane * CELLS;
            int ck = r >> 8, qq = (r >> 6) & 3, row = r & 63;
            const unsigned short* src = (plane ? Blo : Bhi) + (size_t)(n0 + row) * Kp + ck * 32 + qq * 8;
            gload_lds16(src, &sB[(size_t)c * 8]);
        }
        __syncthreads();

        f32x4 acc[2][2] = {};
        #pragma unroll
        for (int ck = 0; ck < NCK; ck++) {
            bf16x8 ah[2], al[2], bh[2], bl[2];
            #pragma unroll
            for (int i = 0; i < 2; i++) {
                int ra = wm * 32 + i * 16 + l16;
                int rb = wn * 32 + i * 16 + l16;
                ah[i] = *(const bf16x8*)&sA[(size_t)(((0 * NCK + ck) * 4 + q) * 64 + ra) * 8];
                al[i] = *(const bf16x8*)&sA[(size_t)(((1 * NCK + ck) * 4 + q) * 64 + ra) * 8];
                bh[i] = *(const bf16x8*)&sB[(size_t)(((0 * NCK + ck) * 4 + q) * 64 + rb) * 8];
                bl[i] = *(const bf16x8*)&sB[(size_t)(((1 * NCK + ck) * 4 + q) * 64 + rb) * 8];
            }
            #pragma unroll
            for (int i = 0; i < 2; i++)
                #pragma unroll
                for (int j = 0; j < 2; j++) {
                    acc[i][j] = __builtin_amdgcn_mfma_f32_16x16x32_bf16(ah[i], bh[j], acc[i][j], 0, 0, 0);
                    acc[i][j] = __builtin_amdgcn_mfma_f32_16x16x32_bf16(ah[i], bl[j], acc[i][j], 0, 0, 0);
                    acc[i][j] = __builtin_amdgcn_mfma_f32_16x16x32_bf16(al[i], bh[j], acc[i][j], 0, 0, 0);
                }
        }

        #pragma unroll
        for (int i = 0; i < 2; i++) {
            int rbase = m0 + wm * 32 + i * 16 + q * 4;
            #pragma unroll
            for (int j = 0; j < 2; j++) {
                int col = n0 + wn * 32 + j * 16 + l16;
                if (col >= Cstride) continue;
                float bv = (col < N) ? bias[col] : 0.0f;
                #pragma unroll
                for (int r = 0; r < 4; r++) {
                    int row = rbase + r;
                    if (row < M) {
                        float v = 0.0f;
                        if (col < N) {
                            v = acc[i][j][r] + bv;
                            if (do_relu) v = fmaxf(v, 0.0f);
                            if (scale) v *= scale[row];
                        }
                        C[(size_t)row * Cstride + col] = v;
                    }
                }
            }
        }
    }
}

// ---------------- segment-max pool (batch sorted), float4 ----------------
__device__ inline int lower_bound_dev(const int* a, int n, int v) {
    int lo = 0, hi = n;
    while (lo < hi) { int mid = (lo + hi) >> 1; if (a[mid] < v) lo = mid + 1; else hi = mid; }
    return lo;
}

__global__ void pool_kernel(const float* __restrict__ H, const int* __restrict__ batch,
                            float* __restrict__ pooled, int n, int G) {
    int g = blockIdx.x;
    int t = threadIdx.x;
    int s = lower_bound_dev(batch, n, g);
    int e = lower_bound_dev(batch, n, g + 1);
    if (t >= 78) return;
    const float4* H4 = (const float4*)H;
    float4 m = {0.f, 0.f, 0.f, 0.f};
    for (int i = s; i < e; i++) {
        float4 v = H4[(size_t)i * 78 + t];
        m.x = fmaxf(m.x, v.x); m.y = fmaxf(m.y, v.y);
        m.z = fmaxf(m.z, v.z); m.w = fmaxf(m.w, v.w);
    }
    ((float4*)pooled)[(size_t)g * 78 + t] = m;
}

// ---------------- FC1: grid (4 col-tiles, 125 graph-tiles); thread = 1 col x 4 graphs ----------------
__global__ __launch_bounds__(256) void fc1_kernel(const float* __restrict__ pooled,
                                                  const float* __restrict__ Wf1,
                                                  const float* __restrict__ bf1,
                                                  float* __restrict__ f1buf) {
    __shared__ float pl[4][312];
    int cb = blockIdx.x, gb = blockIdx.y;
    int t = threadIdx.x;
    for (int i = t; i < 4 * 312; i += 256) {
        int g = i / 312, k = i - g * 312;
        pl[g][k] = pooled[(size_t)(gb * 4 + g) * 312 + k];
    }
    __syncthreads();
    int col = cb * 256 + t;
    float a0 = 0.f, a1 = 0.f, a2 = 0.f, a3 = 0.f;
    #pragma unroll 4
    for (int k = 0; k < 312; k++) {
        float w = Wf1[(size_t)k * 1024 + col];
        a0 += pl[0][k] * w; a1 += pl[1][k] * w; a2 += pl[2][k] * w; a3 += pl[3][k] * w;
    }
    float b = bf1[col];
    int g0 = gb * 4;
    f1buf[(size_t)g0 * 1024 + col]       = fmaxf(a0 + b, 0.f);
    f1buf[(size_t)(g0 + 1) * 1024 + col] = fmaxf(a1 + b, 0.f);
    f1buf[(size_t)(g0 + 2) * 1024 + col] = fmaxf(a2 + b, 0.f);
    f1buf[(size_t)(g0 + 3) * 1024 + col] = fmaxf(a3 + b, 0.f);
}

// ---------------- FC2 k-split: grid (8 k-tiles, 125 graph-tiles); deterministic partials ----------------
__global__ __launch_bounds__(256) void fc2_part_kernel(const float* __restrict__ f1buf,
                                                       const float* __restrict__ Wf2,
                                                       float* __restrict__ partial) {
    __shared__ float f1s[4][128];
    __shared__ float red[256][4];
    int kt = blockIdx.x;
    int gb = blockIdx.y;
    int t = threadIdx.x;
    int col = t & 127, ks = t >> 7;
    for (int i = t; i < 512; i += 256) {
        int g = i >> 7, k = i & 127;
        f1s[g][k] = f1buf[(size_t)(gb * 4 + g) * 1024 + kt * 128 + k];
    }
    __syncthreads();
    float a0 = 0.f, a1 = 0.f, a2 = 0.f, a3 = 0.f;
    const float* w2 = Wf2 + (size_t)(kt * 128 + ks * 64) * 128 + col;
    #pragma unroll 4
    for (int k = 0; k < 64; k++) {
        float w = w2[(size_t)k * 128];
        int kk = ks * 64 + k;
        a0 += f1s[0][kk] * w; a1 += f1s[1][kk] * w; a2 += f1s[2][kk] * w; a3 += f1s[3][kk] * w;
    }
    red[t][0] = a0; red[t][1] = a1; red[t][2] = a2; red[t][3] = a3;
    __syncthreads();
    if (t < 128) {
        #pragma unroll
        for (int g = 0; g < 4; g++)
            partial[((size_t)kt * GRAPHS + gb * 4 + g) * 128 + col] = red[t][g] + red[t + 128][g];
    }
}

__global__ void fc2_reduce_kernel(const float* __restrict__ partial, const float* __restrict__ bf2,
                                  float* __restrict__ out, int total) {
    int i = blockIdx.x * blockDim.x + threadIdx.x;
    if (i < total) {
        float s = bf2[i & 127];
        #pragma unroll
        for (int kt = 0; kt < 8; kt++) s += partial[(size_t)kt * total + i];
        out[i] = s;
    }
}

extern "C" void kernel_launch(void* const* d_in, const int* in_sizes, int n_in,
                              void* d_out, int out_size, void* d_ws, size_t ws_size,
                              hipStream_t stream) {
    const float* x    = (const float*)d_in[0];
    const int*   ei   = (const int*)d_in[1];
    const int*   batch= (const int*)d_in[2];
    const float* W1 = (const float*)d_in[3];  const float* b1  = (const float*)d_in[4];
    const float* W2 = (const float*)d_in[5];  const float* b2  = (const float*)d_in[6];
    const float* W3 = (const float*)d_in[7];  const float* b3  = (const float*)d_in[8];
    const float* Wf1= (const float*)d_in[9];  const float* bf1 = (const float*)d_in[10];
    const float* Wf2= (const float*)d_in[11]; const float* bf2 = (const float*)d_in[12];
    float* out = (float*)d_out;

    const int* srcp = ei;
    const int* dstp = ei + EDGES;

    char* p = (char*)d_ws;
    size_t o = 0;
    auto takeB = [&](size_t bytes) { char* q = p + o; o += (bytes + 255) & ~(size_t)255; return q; };
    int*   cnt      = (int*)takeB(NODES * 4);
    int*   cursor   = (int*)takeB(NODES * 4);
    int*   rowstart = (int*)takeB(NODES * 4);
    int*   bsum     = (int*)takeB(NB * 4);
    int*   boff     = (int*)takeB(NB * 4);
    float* dinv     = (float*)takeB(NODES * 4);
    int*   csr_src  = (int*)takeB(EDGES * 4);
    unsigned short* aggH = (unsigned short*)takeB((size_t)MPAD * 160 * 2);
    unsigned short* aggL = (unsigned short*)takeB((size_t)MPAD * 160 * 2);
    float* xs      = (float*)takeB((size_t)NODES * 80 * 4);
    float* hbuf    = (float*)takeB((size_t)NODES * 312 * 4);
    float* pooled  = (float*)takeB((size_t)GRAPHS * 312 * 4);
    float* f1buf   = (float*)takeB((size_t)GRAPHS * 1024 * 4);
    float* partial = (float*)takeB((size_t)8 * GRAPHS * 128 * 4);
    unsigned short* Wt1h = (unsigned short*)takeB(128 * 96 * 2);
    unsigned short* Wt1l = (unsigned short*)takeB(128 * 96 * 2);
    unsigned short* Wt2h = (unsigned short*)takeB(192 * 96 * 2);
    unsigned short* Wt2l = (unsigned short*)takeB(192 * 96 * 2);
    unsigned short* Wt3h = (unsigned short*)takeB(320 * 160 * 2);
    unsigned short* Wt3l = (unsigned short*)takeB(320 * 160 * 2);
    (void)ws_size;

    hipMemsetAsync(cnt, 0, NODES * sizeof(int), stream);
    hipMemsetAsync(cursor, 0, NODES * sizeof(int), stream);

    wsplit_kernel<<<128, 96, 0, stream>>>(W1, Wt1h, Wt1l, 78, 78, 96);
    wsplit_kernel<<<192, 96, 0, stream>>>(W2, Wt2h, Wt2l, 78, 156, 96);
    wsplit_kernel<<<320, 160, 0, stream>>>(W3, Wt3h, Wt3l, 156, 312, 160);

    count_kernel<<<(EDGES + 255) / 256, 256, 0, stream>>>(dstp, cnt, EDGES);
    scan_bsum_kernel<<<NB, 256, 0, stream>>>(cnt, bsum, NODES);
    scan_top_kernel<<<1, 128, 0, stream>>>(bsum, boff);
    scan_apply_kernel<<<NB, 256, 0, stream>>>(cnt, boff, rowstart, dinv, NODES);
    fill_kernel<<<(EDGES + 255) / 256, 256, 0, stream>>>(srcp, dstp, rowstart, cursor, csr_src, EDGES);

    const int NBLK = MPAD / 64;   // 469
    const int AGRID = NODES / 4;  // 7500

    // layer 1: prescale -> 2 half-row agg passes (L2-resident 4.8MB halves) -> gemm
    prescale_kernel<<<(NODES * 80 + 255) / 256, 256, 0, stream>>>(x, dinv, xs, NODES * 80);
    agg_half<10, 20, 0, 0, 0, 24><<<AGRID, 256, 0, stream>>>(xs, rowstart, cnt, csr_src, dinv, aggH, aggL);
    agg_half<10, 20, 10, 10, 4, 24><<<AGRID, 256, 0, stream>>>(xs, rowstart, cnt, csr_src, dinv, aggH, aggL);
    mfma_gemm_v2<3><<<NBLK, 256, 3 * 16384, stream>>>(aggH, aggL, Wt1h, Wt1l, b1, dinv, hbuf,
                                                      NODES, 78, 80, 2, 1);
    // layer 2 (input stride 80): 2 half-row passes -> gemm (output stride 160)
    agg_half<10, 20, 0, 0, 0, 24><<<AGRID, 256, 0, stream>>>(hbuf, rowstart, cnt, csr_src, dinv, aggH, aggL);
    agg_half<10, 20, 10, 10, 4, 24><<<AGRID, 256, 0, stream>>>(hbuf, rowstart, cnt, csr_src, dinv, aggH, aggL);
    mfma_gemm_v2<3><<<NBLK, 256, 3 * 16384, stream>>>(aggH, aggL, Wt2h, Wt2l, b2, dinv, hbuf,
                                                      NODES, 156, 160, 3, 1);
    // layer 3 (input stride 160, compulsory-bound, single pass)
    agg_split_v3<40, 40><<<AGRID, 256, 0, stream>>>(hbuf, rowstart, cnt, csr_src, dinv, aggH, aggL);
    mfma_gemm_v2<5><<<NBLK, 256, 5 * 16384, stream>>>(aggH, aggL, Wt3h, Wt3l, b3, nullptr, hbuf,
                                                      NODES, 312, 312, 5, 1);

    pool_kernel<<<GRAPHS, 128, 0, stream>>>(hbuf, batch, pooled, NODES, GRAPHS);
    fc1_kernel<<<dim3(4, GRAPHS / 4), 256, 0, stream>>>(pooled, Wf1, bf1, f1buf);
    fc2_part_kernel<<<dim3(8, GRAPHS / 4), 256, 0, stream>>>(f1buf, Wf2, partial);
    fc2_reduce_kernel<<<(GRAPHS * 128 + 255) / 256, 256, 0, stream>>>(partial, bf2, out, GRAPHS * 128);
}

// Round 13
// 374.614 us; speedup vs baseline: 1.0509x; 1.0509x over previous
//
#include <hip/hip_runtime.h>

#define NODES  30000
#define EDGES  480000
#define GRAPHS 500
#define MPAD   30016   // 64*469
#define NB     118     // scan blocks: ceil(30000/256)

typedef __bf16 bf16x8 __attribute__((ext_vector_type(8)));
typedef float  f32x4  __attribute__((ext_vector_type(4)));

__device__ __forceinline__ float4 f4add(float4 a, float4 b) {
    a.x += b.x; a.y += b.y; a.z += b.z; a.w += b.w; return a;
}

// ---------------- fp32 -> bf16 hi/lo split (RNE both halves) ----------------
__device__ __forceinline__ void split_f32(float a, unsigned short& hi, unsigned short& lo) {
    unsigned int u = __float_as_uint(a);
    unsigned int rh = (u + 0x7fffu + ((u >> 16) & 1u)) & 0xffff0000u;
    hi = (unsigned short)(rh >> 16);
    float l = a - __uint_as_float(rh);
    unsigned int ul = __float_as_uint(l);
    lo = (unsigned short)((ul + 0x7fffu + ((ul >> 16) & 1u)) >> 16);
}

__device__ __forceinline__ void gload_lds16(const void* g, void* l) {
    __builtin_amdgcn_global_load_lds(
        (__attribute__((address_space(1))) void*)g,
        (__attribute__((address_space(3))) void*)l, 16, 0, 0);
}

// ---------------- CSR build ----------------
__global__ void count_kernel(const int* __restrict__ dst, int* __restrict__ cnt, int E) {
    int i = blockIdx.x * blockDim.x + threadIdx.x;
    if (i < E) atomicAdd(&cnt[dst[i]], 1);
}

__global__ __launch_bounds__(256) void scan_bsum_kernel(const int* __restrict__ cnt,
                                                        int* __restrict__ bsum, int n) {
    __shared__ int buf[256];
    int t = threadIdx.x;
    int i = blockIdx.x * 256 + t;
    buf[t] = (i < n) ? cnt[i] : 0;
    __syncthreads();
    for (int ofs = 128; ofs > 0; ofs >>= 1) {
        if (t < ofs) buf[t] += buf[t + ofs];
        __syncthreads();
    }
    if (t == 0) bsum[blockIdx.x] = buf[0];
}

__global__ __launch_bounds__(128) void scan_top_kernel(const int* __restrict__ bsum,
                                                       int* __restrict__ boff) {
    __shared__ int buf[128];
    int t = threadIdx.x;
    int own = (t < NB) ? bsum[t] : 0;
    buf[t] = own;
    __syncthreads();
    for (int ofs = 1; ofs < 128; ofs <<= 1) {
        int v = (t >= ofs) ? buf[t - ofs] : 0;
        __syncthreads();
        buf[t] += v;
        __syncthreads();
    }
    if (t < NB) boff[t] = buf[t] - own;
}

__global__ __launch_bounds__(256) void scan_apply_kernel(const int* __restrict__ cnt,
                                                         const int* __restrict__ boff,
                                                         int* __restrict__ rowstart,
                                                         float* __restrict__ dinv, int n) {
    __shared__ int buf[256];
    int t = threadIdx.x;
    int i = blockIdx.x * 256 + t;
    int own = (i < n) ? cnt[i] : 0;
    buf[t] = own;
    __syncthreads();
    for (int ofs = 1; ofs < 256; ofs <<= 1) {
        int v = (t >= ofs) ? buf[t - ofs] : 0;
        __syncthreads();
        buf[t] += v;
        __syncthreads();
    }
    if (i < n) {
        rowstart[i] = boff[blockIdx.x] + buf[t] - own;
        dinv[i] = rsqrtf((float)own + 1.0f);
    }
}

__global__ void fill_kernel(const int* __restrict__ src, const int* __restrict__ dst,
                            const int* __restrict__ rowstart, int* __restrict__ cursor,
                            int* __restrict__ csr_src, int E) {
    int i = blockIdx.x * blockDim.x + threadIdx.x;
    if (i < E) {
        int d = dst[i];
        int pos = atomicAdd(&cursor[d], 1);
        csr_src[rowstart[d] + pos] = src[i];
    }
}

// ---------------- pre-scale into padded stride-80 layout ----------------
__global__ void prescale_kernel(const float* __restrict__ X, const float* __restrict__ dinv,
                                float* __restrict__ Xs, int total) {
    int i = blockIdx.x * blockDim.x + threadIdx.x;
    if (i < total) {
        int node = i / 80;
        int c = i - node * 80;
        Xs[i] = (c < 78) ? X[node * 78 + c] * dinv[node] : 0.0f;
    }
}

// ---------------- weight split+transpose ----------------
__global__ void wsplit_kernel(const float* __restrict__ W, unsigned short* __restrict__ hi,
                              unsigned short* __restrict__ lo, int K, int N, int Kp) {
    int n = blockIdx.x, k = threadIdx.x;
    float v = (n < N && k < K) ? W[(size_t)k * N + n] : 0.0f;
    unsigned short h, l;
    split_f32(v, h, l);
    hi[(size_t)n * Kp + k] = h;
    lo[(size_t)n * Kp + k] = l;
}

// ---------------- aggregation: float4 gathers, EPI edges per instruction, 8-deep MLP ----------------
template <int DV, int KQ>
__global__ __launch_bounds__(256) void agg_split_v3(
    const float* __restrict__ Xs, const int* __restrict__ rowstart,
    const int* __restrict__ cnt, const int* __restrict__ csr_src,
    const float* __restrict__ dinv,
    unsigned short* __restrict__ ohi, unsigned short* __restrict__ olo)
{
    constexpr int EPI = 64 / DV;
    constexpr int Kp = KQ * 4;
    int node = blockIdx.x * 4 + (threadIdx.x >> 6);
    int lane = threadIdx.x & 63;
    int sub = lane / DV;
    int c4 = lane - sub * DV;
    const float4* X4 = (const float4*)Xs;

    float4 acc0 = {0.f, 0.f, 0.f, 0.f}, acc1 = {0.f, 0.f, 0.f, 0.f};
    float4 acc2 = {0.f, 0.f, 0.f, 0.f}, acc3 = {0.f, 0.f, 0.f, 0.f};
    int s = rowstart[node];
    int e = s + cnt[node];

    if (sub < EPI) {
        if (sub == 0) acc0 = X4[(size_t)node * DV + c4];
        int j = s;
        for (; j + 8 * EPI <= e; j += 8 * EPI) {     // 8 gathers in flight
            int i0 = csr_src[j + sub],           i1 = csr_src[j + EPI + sub];
            int i2 = csr_src[j + 2 * EPI + sub], i3 = csr_src[j + 3 * EPI + sub];
            int i4 = csr_src[j + 4 * EPI + sub], i5 = csr_src[j + 5 * EPI + sub];
            int i6 = csr_src[j + 6 * EPI + sub], i7 = csr_src[j + 7 * EPI + sub];
            float4 x0 = X4[(size_t)i0 * DV + c4], x1 = X4[(size_t)i1 * DV + c4];
            float4 x2 = X4[(size_t)i2 * DV + c4], x3 = X4[(size_t)i3 * DV + c4];
            float4 x4 = X4[(size_t)i4 * DV + c4], x5 = X4[(size_t)i5 * DV + c4];
            float4 x6 = X4[(size_t)i6 * DV + c4], x7 = X4[(size_t)i7 * DV + c4];
            acc0 = f4add(acc0, x0); acc1 = f4add(acc1, x1);
            acc2 = f4add(acc2, x2); acc3 = f4add(acc3, x3);
            acc0 = f4add(acc0, x4); acc1 = f4add(acc1, x5);
            acc2 = f4add(acc2, x6); acc3 = f4add(acc3, x7);
        }
        for (; j + 4 * EPI <= e; j += 4 * EPI) {
            int i0 = csr_src[j + sub],           i1 = csr_src[j + EPI + sub];
            int i2 = csr_src[j + 2 * EPI + sub], i3 = csr_src[j + 3 * EPI + sub];
            float4 x0 = X4[(size_t)i0 * DV + c4], x1 = X4[(size_t)i1 * DV + c4];
            float4 x2 = X4[(size_t)i2 * DV + c4], x3 = X4[(size_t)i3 * DV + c4];
            acc0 = f4add(acc0, x0); acc1 = f4add(acc1, x1);
            acc2 = f4add(acc2, x2); acc3 = f4add(acc3, x3);
        }
        for (; j < e; j += EPI) {
            int jj = j + sub;
            if (jj < e) {
                int idx = csr_src[jj];
                acc0 = f4add(acc0, X4[(size_t)idx * DV + c4]);
            }
        }
    }
    float4 acc = f4add(f4add(acc0, acc1), f4add(acc2, acc3));

    if constexpr (EPI > 1) {
        // read ALL sources before accumulating (lanes < DV have sources < 64: no wrap, no RAW)
        float sx[EPI - 1], sy[EPI - 1], sz[EPI - 1], sw[EPI - 1];
        #pragma unroll
        for (int sft = 1; sft < EPI; sft++) {
            sx[sft - 1] = __shfl(acc.x, lane + sft * DV);
            sy[sft - 1] = __shfl(acc.y, lane + sft * DV);
            sz[sft - 1] = __shfl(acc.z, lane + sft * DV);
            sw[sft - 1] = __shfl(acc.w, lane + sft * DV);
        }
        #pragma unroll
        for (int sft = 1; sft < EPI; sft++) {
            acc.x += sx[sft - 1];
            acc.y += sy[sft - 1];
            acc.z += sz[sft - 1];
            acc.w += sw[sft - 1];
        }
    }

    if (lane < DV) {
        float di = dinv[node];
        ushort4 h4, l4;
        split_f32(acc.x * di, h4.x, l4.x);
        split_f32(acc.y * di, h4.y, l4.y);
        split_f32(acc.z * di, h4.z, l4.z);
        split_f32(acc.w * di, h4.w, l4.w);
        *(ushort4*)&ohi[(size_t)node * Kp + lane * 4] = h4;
        *(ushort4*)&olo[(size_t)node * Kp + lane * 4] = l4;
    } else if (lane < KQ) {
        ushort4 z = {0, 0, 0, 0};
        *(ushort4*)&ohi[(size_t)node * Kp + lane * 4] = z;
        *(ushort4*)&olo[(size_t)node * Kp + lane * 4] = z;
    }
}

// ---------------- split-bf16 MFMA GEMM: row-persistent, in-kernel column loop ----------------
template <int NCK>
__global__ __launch_bounds__(256) void mfma_gemm_v2(
    const unsigned short* __restrict__ Ahi, const unsigned short* __restrict__ Alo,
    const unsigned short* __restrict__ Bhi, const unsigned short* __restrict__ Blo,
    const float* __restrict__ bias, const float* __restrict__ scale,
    float* __restrict__ C, int M, int N, int Cstride, int nN, int do_relu)
{
    constexpr int Kp = NCK * 32;
    constexpr int CELLS = NCK * 256;
    extern __shared__ unsigned short smem[];
    unsigned short* sA = smem;
    unsigned short* sB = smem + 2 * CELLS * 8;

    int t = threadIdx.x;
    int wv = t >> 6, ln = t & 63;
    int q = ln >> 4, l16 = ln & 15;
    int wm = wv & 1, wn = wv >> 1;
    int m0 = blockIdx.x * 64;

    #pragma unroll
    for (int i = 0; i < 2 * NCK; i++) {
        int c = i * 256 + t;
        int plane = c / CELLS;
        int r = c - plane * CELLS;
        int ck = r >> 8, qq = (r >> 6) & 3, row = r & 63;
        const unsigned short* src = (plane ? Alo : Ahi) + (size_t)(m0 + row) * Kp + ck * 32 + qq * 8;
        gload_lds16(src, &sA[(size_t)c * 8]);
    }

    for (int nt = 0; nt < nN; nt++) {
        int n0 = nt * 64;
        if (nt > 0) __syncthreads();
        #pragma unroll
        for (int i = 0; i < 2 * NCK; i++) {
            int c = i * 256 + t;
            int plane = c / CELLS;
            int r = c - plane * CELLS;
            int ck = r >> 8, qq = (r >> 6) & 3, row = r & 63;
            const unsigned short* src = (plane ? Blo : Bhi) + (size_t)(n0 + row) * Kp + ck * 32 + qq * 8;
            gload_lds16(src, &sB[(size_t)c * 8]);
        }
        __syncthreads();

        f32x4 acc[2][2] = {};
        #pragma unroll
        for (int ck = 0; ck < NCK; ck++) {
            bf16x8 ah[2], al[2], bh[2], bl[2];
            #pragma unroll
            for (int i = 0; i < 2; i++) {
                int ra = wm * 32 + i * 16 + l16;
                int rb = wn * 32 + i * 16 + l16;
                ah[i] = *(const bf16x8*)&sA[(size_t)(((0 * NCK + ck) * 4 + q) * 64 + ra) * 8];
                al[i] = *(const bf16x8*)&sA[(size_t)(((1 * NCK + ck) * 4 + q) * 64 + ra) * 8];
                bh[i] = *(const bf16x8*)&sB[(size_t)(((0 * NCK + ck) * 4 + q) * 64 + rb) * 8];
                bl[i] = *(const bf16x8*)&sB[(size_t)(((1 * NCK + ck) * 4 + q) * 64 + rb) * 8];
            }
            #pragma unroll
            for (int i = 0; i < 2; i++)
                #pragma unroll
                for (int j = 0; j < 2; j++) {
                    acc[i][j] = __builtin_amdgcn_mfma_f32_16x16x32_bf16(ah[i], bh[j], acc[i][j], 0, 0, 0);
                    acc[i][j] = __builtin_amdgcn_mfma_f32_16x16x32_bf16(ah[i], bl[j], acc[i][j], 0, 0, 0);
                    acc[i][j] = __builtin_amdgcn_mfma_f32_16x16x32_bf16(al[i], bh[j], acc[i][j], 0, 0, 0);
                }
        }

        #pragma unroll
        for (int i = 0; i < 2; i++) {
            int rbase = m0 + wm * 32 + i * 16 + q * 4;
            #pragma unroll
            for (int j = 0; j < 2; j++) {
                int col = n0 + wn * 32 + j * 16 + l16;
                if (col >= Cstride) continue;
                float bv = (col < N) ? bias[col] : 0.0f;
                #pragma unroll
                for (int r = 0; r < 4; r++) {
                    int row = rbase + r;
                    if (row < M) {
                        float v = 0.0f;
                        if (col < N) {
                            v = acc[i][j][r] + bv;
                            if (do_relu) v = fmaxf(v, 0.0f);
                            if (scale) v *= scale[row];
                        }
                        C[(size_t)row * Cstride + col] = v;
                    }
                }
            }
        }
    }
}

// ---------------- segment-max pool (batch sorted), float4 ----------------
__device__ inline int lower_bound_dev(const int* a, int n, int v) {
    int lo = 0, hi = n;
    while (lo < hi) { int mid = (lo + hi) >> 1; if (a[mid] < v) lo = mid + 1; else hi = mid; }
    return lo;
}

__global__ void pool_kernel(const float* __restrict__ H, const int* __restrict__ batch,
                            float* __restrict__ pooled, int n, int G) {
    int g = blockIdx.x;
    int t = threadIdx.x;
    int s = lower_bound_dev(batch, n, g);
    int e = lower_bound_dev(batch, n, g + 1);
    if (t >= 78) return;
    const float4* H4 = (const float4*)H;
    float4 m = {0.f, 0.f, 0.f, 0.f};
    for (int i = s; i < e; i++) {
        float4 v = H4[(size_t)i * 78 + t];
        m.x = fmaxf(m.x, v.x); m.y = fmaxf(m.y, v.y);
        m.z = fmaxf(m.z, v.z); m.w = fmaxf(m.w, v.w);
    }
    ((float4*)pooled)[(size_t)g * 78 + t] = m;
}

// ---------------- FC1: grid (4 col-tiles, 125 graph-tiles); thread = 1 col x 4 graphs ----------------
__global__ __launch_bounds__(256) void fc1_kernel(const float* __restrict__ pooled,
                                                  const float* __restrict__ Wf1,
                                                  const float* __restrict__ bf1,
                                                  float* __restrict__ f1buf) {
    __shared__ float pl[4][312];
    int cb = blockIdx.x, gb = blockIdx.y;
    int t = threadIdx.x;
    for (int i = t; i < 4 * 312; i += 256) {
        int g = i / 312, k = i - g * 312;
        pl[g][k] = pooled[(size_t)(gb * 4 + g) * 312 + k];
    }
    __syncthreads();
    int col = cb * 256 + t;
    float a0 = 0.f, a1 = 0.f, a2 = 0.f, a3 = 0.f;
    #pragma unroll 4
    for (int k = 0; k < 312; k++) {
        float w = Wf1[(size_t)k * 1024 + col];
        a0 += pl[0][k] * w; a1 += pl[1][k] * w; a2 += pl[2][k] * w; a3 += pl[3][k] * w;
    }
    float b = bf1[col];
    int g0 = gb * 4;
    f1buf[(size_t)g0 * 1024 + col]       = fmaxf(a0 + b, 0.f);
    f1buf[(size_t)(g0 + 1) * 1024 + col] = fmaxf(a1 + b, 0.f);
    f1buf[(size_t)(g0 + 2) * 1024 + col] = fmaxf(a2 + b, 0.f);
    f1buf[(size_t)(g0 + 3) * 1024 + col] = fmaxf(a3 + b, 0.f);
}

// ---------------- FC2 k-split: grid (8 k-tiles, 125 graph-tiles); deterministic partials ----------------
__global__ __launch_bounds__(256) void fc2_part_kernel(const float* __restrict__ f1buf,
                                                       const float* __restrict__ Wf2,
                                                       float* __restrict__ partial) {
    __shared__ float f1s[4][128];
    __shared__ float red[256][4];
    int kt = blockIdx.x;
    int gb = blockIdx.y;
    int t = threadIdx.x;
    int col = t & 127, ks = t >> 7;
    for (int i = t; i < 512; i += 256) {
        int g = i >> 7, k = i & 127;
        f1s[g][k] = f1buf[(size_t)(gb * 4 + g) * 1024 + kt * 128 + k];
    }
    __syncthreads();
    float a0 = 0.f, a1 = 0.f, a2 = 0.f, a3 = 0.f;
    const float* w2 = Wf2 + (size_t)(kt * 128 + ks * 64) * 128 + col;
    #pragma unroll 4
    for (int k = 0; k < 64; k++) {
        float w = w2[(size_t)k * 128];
        int kk = ks * 64 + k;
        a0 += f1s[0][kk] * w; a1 += f1s[1][kk] * w; a2 += f1s[2][kk] * w; a3 += f1s[3][kk] * w;
    }
    red[t][0] = a0; red[t][1] = a1; red[t][2] = a2; red[t][3] = a3;
    __syncthreads();
    if (t < 128) {
        #pragma unroll
        for (int g = 0; g < 4; g++)
            partial[((size_t)kt * GRAPHS + gb * 4 + g) * 128 + col] = red[t][g] + red[t + 128][g];
    }
}

__global__ void fc2_reduce_kernel(const float* __restrict__ partial, const float* __restrict__ bf2,
                                  float* __restrict__ out, int total) {
    int i = blockIdx.x * blockDim.x + threadIdx.x;
    if (i < total) {
        float s = bf2[i & 127];
        #pragma unroll
        for (int kt = 0; kt < 8; kt++) s += partial[(size_t)kt * total + i];
        out[i] = s;
    }
}

extern "C" void kernel_launch(void* const* d_in, const int* in_sizes, int n_in,
                              void* d_out, int out_size, void* d_ws, size_t ws_size,
                              hipStream_t stream) {
    const float* x    = (const float*)d_in[0];
    const int*   ei   = (const int*)d_in[1];
    const int*   batch= (const int*)d_in[2];
    const float* W1 = (const float*)d_in[3];  const float* b1  = (const float*)d_in[4];
    const float* W2 = (const float*)d_in[5];  const float* b2  = (const float*)d_in[6];
    const float* W3 = (const float*)d_in[7];  const float* b3  = (const float*)d_in[8];
    const float* Wf1= (const float*)d_in[9];  const float* bf1 = (const float*)d_in[10];
    const float* Wf2= (const float*)d_in[11]; const float* bf2 = (const float*)d_in[12];
    float* out = (float*)d_out;

    const int* srcp = ei;
    const int* dstp = ei + EDGES;

    char* p = (char*)d_ws;
    size_t o = 0;
    auto takeB = [&](size_t bytes) { char* q = p + o; o += (bytes + 255) & ~(size_t)255; return q; };
    int*   cnt      = (int*)takeB(NODES * 4);
    int*   cursor   = (int*)takeB(NODES * 4);
    int*   rowstart = (int*)takeB(NODES * 4);
    int*   bsum     = (int*)takeB(NB * 4);
    int*   boff     = (int*)takeB(NB * 4);
    float* dinv     = (float*)takeB(NODES * 4);
    int*   csr_src  = (int*)takeB(EDGES * 4);
    unsigned short* aggH = (unsigned short*)takeB((size_t)MPAD * 160 * 2);
    unsigned short* aggL = (unsigned short*)takeB((size_t)MPAD * 160 * 2);
    float* xs      = (float*)takeB((size_t)NODES * 80 * 4);
    float* hbuf    = (float*)takeB((size_t)NODES * 312 * 4);
    float* pooled  = (float*)takeB((size_t)GRAPHS * 312 * 4);
    float* f1buf   = (float*)takeB((size_t)GRAPHS * 1024 * 4);
    float* partial = (float*)takeB((size_t)8 * GRAPHS * 128 * 4);
    unsigned short* Wt1h = (unsigned short*)takeB(128 * 96 * 2);
    unsigned short* Wt1l = (unsigned short*)takeB(128 * 96 * 2);
    unsigned short* Wt2h = (unsigned short*)takeB(192 * 96 * 2);
    unsigned short* Wt2l = (unsigned short*)takeB(192 * 96 * 2);
    unsigned short* Wt3h = (unsigned short*)takeB(320 * 160 * 2);
    unsigned short* Wt3l = (unsigned short*)takeB(320 * 160 * 2);
    (void)ws_size;

    hipMemsetAsync(cnt, 0, NODES * sizeof(int), stream);
    hipMemsetAsync(cursor, 0, NODES * sizeof(int), stream);

    wsplit_kernel<<<128, 96, 0, stream>>>(W1, Wt1h, Wt1l, 78, 78, 96);
    wsplit_kernel<<<192, 96, 0, stream>>>(W2, Wt2h, Wt2l, 78, 156, 96);
    wsplit_kernel<<<320, 160, 0, stream>>>(W3, Wt3h, Wt3l, 156, 312, 160);

    count_kernel<<<(EDGES + 255) / 256, 256, 0, stream>>>(dstp, cnt, EDGES);
    scan_bsum_kernel<<<NB, 256, 0, stream>>>(cnt, bsum, NODES);
    scan_top_kernel<<<1, 128, 0, stream>>>(bsum, boff);
    scan_apply_kernel<<<NB, 256, 0, stream>>>(cnt, boff, rowstart, dinv, NODES);
    fill_kernel<<<(EDGES + 255) / 256, 256, 0, stream>>>(srcp, dstp, rowstart, cursor, csr_src, EDGES);

    const int NBLK = MPAD / 64;   // 469
    const int AGRID = NODES / 4;  // 7500

    // layer 1: prescale (stride 80, zero pad) -> agg -> gemm (C stride 80, pad zeroed)
    prescale_kernel<<<(NODES * 80 + 255) / 256, 256, 0, stream>>>(x, dinv, xs, NODES * 80);
    agg_split_v3<20, 24><<<AGRID, 256, 0, stream>>>(xs, rowstart, cnt, csr_src, dinv, aggH, aggL);
    mfma_gemm_v2<3><<<NBLK, 256, 3 * 16384, stream>>>(aggH, aggL, Wt1h, Wt1l, b1, dinv, hbuf,
                                                      NODES, 78, 80, 2, 1);
    // layer 2 (input stride 80, output stride 160)
    agg_split_v3<20, 24><<<AGRID, 256, 0, stream>>>(hbuf, rowstart, cnt, csr_src, dinv, aggH, aggL);
    mfma_gemm_v2<3><<<NBLK, 256, 3 * 16384, stream>>>(aggH, aggL, Wt2h, Wt2l, b2, dinv, hbuf,
                                                      NODES, 156, 160, 3, 1);
    // layer 3 (input stride 160, output stride 312, unscaled for pooling)
    agg_split_v3<40, 40><<<AGRID, 256, 0, stream>>>(hbuf, rowstart, cnt, csr_src, dinv, aggH, aggL);
    mfma_gemm_v2<5><<<NBLK, 256, 5 * 16384, stream>>>(aggH, aggL, Wt3h, Wt3l, b3, nullptr, hbuf,
                                                      NODES, 312, 312, 5, 1);

    pool_kernel<<<GRAPHS, 128, 0, stream>>>(hbuf, batch, pooled, NODES, GRAPHS);
    fc1_kernel<<<dim3(4, GRAPHS / 4), 256, 0, stream>>>(pooled, Wf1, bf1, f1buf);
    fc2_part_kernel<<<dim3(8, GRAPHS / 4), 256, 0, stream>>>(f1buf, Wf2, partial);
    fc2_reduce_kernel<<<(GRAPHS * 128 + 255) / 256, 256, 0, stream>>>(partial, bf2, out, GRAPHS * 128);
}